// Round 4
// baseline (120.342 us; speedup 1.0000x reference)
//
#include <hip/hip_runtime.h>
#include <hip/hip_bf16.h>

// B=4, C=64, O=64, H=W=128, K=3, KK=9, PAD=1
// MFMA 16x16x32 bf16: A[m=lane&15][k=(lane>>4)*8+j], B[n=lane&15][k=...],
// C/D: col(n)=lane&15, row(m)=(lane>>4)*4+reg
// kappa = s*32 + q*8 + j  ->  tap = s>>1, c = (s&1)*32 + q*8 + j
//
// ws layout (bytes):
//   xBp  [4][130][130][64] bf16 : ofs 0        (8.65 MB zero-halo padded NHWC bf16 of x)
//   Wb   [4][18][64][8]   bf16  : ofs 8652800  (deform weight B-frags)
//   OWb  [2][18][64][8]   bf16  : ofs 8726528  (offset_w B-frags)
//   off_g[4][128][18][128] f32  : ofs 8763392  (offset-conv output, 4.72 MB)

typedef short short8 __attribute__((ext_vector_type(8)));
typedef short short4v __attribute__((ext_vector_type(4)));
typedef float f32x4 __attribute__((ext_vector_type(4)));

static __device__ inline short bf16s(float f) {
    __hip_bfloat16 h = __float2bfloat16(f);
    return *(short*)&h;
}
static __device__ inline float lo2f(unsigned u) { return __uint_as_float(u << 16); }
static __device__ inline float hi2f(unsigned u) { return __uint_as_float(u & 0xffff0000u); }

// ---------------------------------------------------------------- prep (bf16 B-fragment packing)
__global__ void prep_kernel(const float* __restrict__ offset_w, // [18][64][9]
                            const float* __restrict__ weight,   // [64][64][9]
                            __hip_bfloat16* __restrict__ Wb,    // [4][18][64][8]
                            __hip_bfloat16* __restrict__ OWb)   // [2][18][64][8]
{
    int id = blockIdx.x * 256 + threadIdx.x;
    if (id < 36864) {
        int j    = id & 7;
        int lane = (id >> 3) & 63;
        int id3  = id >> 9;
        int s    = id3 % 18;
        int otile = id3 / 18;
        int n = lane & 15, q = lane >> 4;
        int kap = s * 32 + q * 8 + j;      // kappa = k*64 + c
        int k = kap >> 6, c = kap & 63;
        int o = otile * 16 + n;
        Wb[id] = __float2bfloat16(weight[(o * 64 + c) * 9 + k]);
    }
    int id2 = id - 36864;
    if (id2 >= 0 && id2 < 18432) {
        int j    = id2 & 7;
        int lane = (id2 >> 3) & 63;
        int id3  = id2 >> 9;
        int s    = id3 % 18;
        int ntile = id3 / 18;
        int n = lane & 15, q = lane >> 4;
        int kap = s * 32 + q * 8 + j;
        int k = kap >> 6, c = kap & 63;
        int o = ntile * 16 + n;
        float v = (o < 18) ? offset_w[(o * 64 + c) * 9 + k] : 0.0f;
        OWb[id2] = __float2bfloat16(v);
    }
}

// ---------------------------------------------------------------- NCHW f32 -> padded NHWC bf16 (zero halo)
// grid = 4*130 rows; rows 0/129 = zero halo rows; interior rows also zero cols 0/129.
__global__ void transpose_kernel(const float* __restrict__ x, __hip_bfloat16* __restrict__ xBp)
{
    __shared__ __align__(16) float lds[128 * 65];
    int blk = blockIdx.x;               // b*130 + r
    int b = blk / 130, r = blk - b * 130;
    int t = threadIdx.x;
    unsigned* rowp = (unsigned*)(xBp + (size_t)(b * 130 + r) * 130 * 64); // 4160 dwords per row
    if (r == 0 || r == 129) {           // full zero row (halo)
        uint4 z = {0u, 0u, 0u, 0u};
        for (int i = 0; i < 5; ++i) {
            int e = i * 256 + t;
            if (e < 1040) ((uint4*)rowp)[e] = z;
        }
        return;
    }
    int h = r - 1;
    int w = t & 127, chalf = t >> 7;
    for (int i = 0; i < 32; ++i) {
        int c = i * 2 + chalf;
        lds[w * 65 + c] = x[((b * 64 + c) * 128 + h) * 128 + w];
    }
    __syncthreads();
    unsigned* dst = rowp + 32;          // col 1 (each col = 64 shorts = 32 dwords)
    for (int i = 0; i < 16; ++i) {
        int L = i * 256 + t;            // L = ww*32 + c2
        int ww = L >> 5, c2 = L & 31;
        float f0 = lds[ww * 65 + c2 * 2];
        float f1 = lds[ww * 65 + c2 * 2 + 1];
        unsigned pk = ((unsigned)bf16s(f0) & 0xffffu) | ((unsigned)bf16s(f1) << 16);
        dst[L] = pk;
    }
    if (t < 64) {                       // zero halo cols 0 and 129
        int col = (t >> 5) * 129;
        rowp[col * 32 + (t & 31)] = 0u;
    }
}

// ---------------------------------------------------------------- standalone offset conv via MFMA
// grid = 4*128*2; block handles 64 px of one row; 4 waves x 16 px; each wave does both o-tiles.
// Writes off_g[b][h][o][w] f32 (o<18).
__global__ __launch_bounds__(256, 4) void offconv_kernel(
    const __hip_bfloat16* __restrict__ xBp, // [4][130][130][64]
    const __hip_bfloat16* __restrict__ OWb, // [2][18][64][8]
    const float* __restrict__ offset_b,     // [18]
    float* __restrict__ off_g)              // [4][128][18][128]
{
    __shared__ __align__(16) short patch[198 * 80];  // 3 rows x 66 cols, stride 80 shorts; 31680 B

    int t = threadIdx.x, wv = t >> 6, lane = t & 63;
    int bid = blockIdx.x;               // (b*128+h)*2 + half
    int half = bid & 1;
    int bh = bid >> 1;
    int b = bh >> 7, h = bh & 127;
    int w0 = half * 64;

    // stage 198 px (padded rows h..h+2, padded cols w0..w0+65), no bounds checks (halo is zero)
    for (int i = 0; i < 7; ++i) {
        int e = i * 256 + t;            // 16-B chunk id; 198*8 = 1584 chunks
        if (e < 1584) {
            int px = e >> 3, part = e & 7;
            int prow = px / 66, pcol = px - prow * 66;
            const uint4* src = (const uint4*)(xBp +
                (size_t)((b * 130 + h + prow) * 130 + w0 + pcol) * 64 + part * 8);
            *(uint4*)&patch[px * 80 + part * 8] = *src;
        }
    }
    __syncthreads();

    int n = lane & 15, q = lane >> 4;
    const short8* Bw = (const short8*)OWb;   // [2][18][64]
    f32x4 acc0 = {0.f, 0.f, 0.f, 0.f};
    f32x4 acc1 = {0.f, 0.f, 0.f, 0.f};
#pragma unroll
    for (int s = 0; s < 18; ++s) {
        int k = s >> 1;
        int ky = k / 3, kx = k - ky * 3;
        int pix = ky * 66 + wv * 16 + n + kx;
        const short8 a = *(const short8*)&patch[pix * 80 + (s & 1) * 32 + q * 8];
        acc0 = __builtin_amdgcn_mfma_f32_16x16x32_bf16(a, Bw[(0 * 18 + s) * 64 + lane], acc0, 0, 0, 0);
        acc1 = __builtin_amdgcn_mfma_f32_16x16x32_bf16(a, Bw[(1 * 18 + s) * 64 + lane], acc1, 0, 0, 0);
    }
    // C/D: col = o = lane&15, rows = pixels q*4+r  -> float4 store along w
    float* og = off_g + ((size_t)(b * 128 + h) * 18) * 128 + w0 + wv * 16 + q * 4;
    {
        float bo = offset_b[n];
        float4 st = {acc0[0] + bo, acc0[1] + bo, acc0[2] + bo, acc0[3] + bo};
        *(float4*)&og[n * 128] = st;
    }
    if (n < 2) {
        int o = 16 + n;
        float bo = offset_b[o];
        float4 st = {acc1[0] + bo, acc1[1] + bo, acc1[2] + bo, acc1[3] + bo};
        *(float4*)&og[o * 128] = st;
    }
}

// ---------------------------------------------------------------- fused sampling + deformable conv
// block = 16x1 row tile; 4 waves; grid = 4*128*8 = 4096
// LDS = sampB 23040 + offL 1152 = 24192 B
__global__ __launch_bounds__(256, 6) void deform_kernel(
    const __hip_bfloat16* __restrict__ xBp, // [4][130][130][64] padded NHWC bf16
    const __hip_bfloat16* __restrict__ Wb,  // [4][18][64][8]
    const float* __restrict__ off_g,        // [4][128][18][128]
    const float* __restrict__ bias,         // [64]
    float* __restrict__ out)                // [4][64][128][128] NCHW
{
    __shared__ __align__(16) short sampB[18 * 16 * 40];  // 23040 B
    __shared__ __align__(16) float offL[288];            // [o][p]

    int t = threadIdx.x, wv = t >> 6, lane = t & 63;
    int bid = blockIdx.x;            // b*1024 + h*8 + tx
    int b  = bid >> 10;
    int h  = (bid >> 3) & 127;
    int w0 = (bid & 7) << 4;

    // ---- phase 0: load this tile's 18x16 offsets (288 floats, 256 threads -> strided loop!)
    for (int e = t; e < 288; e += 256) {
        int o = e >> 4, p = e & 15;
        offL[o * 16 + p] = off_g[((size_t)((b * 128 + h) * 18 + o)) * 128 + w0 + p];
    }
    __syncthreads();

    // ---- phase 1: sampling; 16-lane group g owns pixel p=wv*4+g; lane c4 owns ch 4c4..4c4+3
    // Zero-halo padding: clamp coords to [-1,128]; halo reads return 0 == reference's valid-masking.
    {
        int g = lane >> 4, c4 = lane & 15;
        int p = wv * 4 + g;
        const __hip_bfloat16* xb4 = xBp + (size_t)b * (130 * 130 * 64) + c4 * 4 + 131 * 64;

        float offy[9], offx[9];
#pragma unroll
        for (int k = 0; k < 9; ++k) {
            offy[k] = offL[(2 * k) * 16 + p];
            offx[k] = offL[(2 * k + 1) * 16 + p];
        }

#pragma unroll
        for (int k = 0; k < 9; ++k) {
            float py = (float)(h - 1 + (k / 3)) + offy[k];
            float px = (float)(w0 + p - 1 + (k % 3)) + offx[k];
            float y0f = floorf(py), x0f = floorf(px);
            float wy1 = py - y0f, wx1 = px - x0f;
            float wy0 = 1.0f - wy1, wx0 = 1.0f - wx1;
            int iy = (int)y0f, ix = (int)x0f;
            int iy0 = min(max(iy, -1), 128);
            int ix0 = min(max(ix, -1), 128);
            int iy1 = min(max(iy + 1, -1), 128);
            int ix1 = min(max(ix + 1, -1), 128);
            int rb0 = iy0 * 130, rb1 = iy1 * 130;
            int e00 = (rb0 + ix0) * 64;
            int e01 = (rb0 + ix1) * 64;
            int e10 = (rb1 + ix0) * 64;
            int e11 = (rb1 + ix1) * 64;
            float wa  = wy0 * wx0;
            float wb_ = wy0 * wx1;
            float wc  = wy1 * wx0;
            float wd  = wy1 * wx1;

            uint2 r0 = *(const uint2*)(xb4 + e00);
            uint2 r1 = *(const uint2*)(xb4 + e01);
            uint2 r2 = *(const uint2*)(xb4 + e10);
            uint2 r3 = *(const uint2*)(xb4 + e11);

            float s0 = fmaf(wd, lo2f(r3.x), fmaf(wc, lo2f(r2.x), fmaf(wb_, lo2f(r1.x), wa * lo2f(r0.x))));
            float s1 = fmaf(wd, hi2f(r3.x), fmaf(wc, hi2f(r2.x), fmaf(wb_, hi2f(r1.x), wa * hi2f(r0.x))));
            float s2 = fmaf(wd, lo2f(r3.y), fmaf(wc, lo2f(r2.y), fmaf(wb_, lo2f(r1.y), wa * lo2f(r0.y))));
            float s3 = fmaf(wd, hi2f(r3.y), fmaf(wc, hi2f(r2.y), fmaf(wb_, hi2f(r1.y), wa * hi2f(r0.y))));
            int s = 2 * k + (c4 >> 3);
            short4v pk = { bf16s(s0), bf16s(s1), bf16s(s2), bf16s(s3) };
            *(short4v*)&sampB[(s * 16 + p) * 40 + (c4 & 7) * 4] = pk;
        }
    }
    __syncthreads();

    // ---- phase 2: einsum via MFMA; wave wv = o-tile; 18 K-steps
    {
        int n = lane & 15, q = lane >> 4;
        int arow = n * 40 + q * 8;          // A: m = pixel = lane&15
        const short8* BwW = (const short8*)Wb + (wv * 18) * 64 + lane;
        f32x4 acc = {0.f, 0.f, 0.f, 0.f};
#pragma unroll
        for (int s = 0; s < 18; ++s) {
            const short8 a = *(const short8*)&sampB[s * 640 + arow];
            acc = __builtin_amdgcn_mfma_f32_16x16x32_bf16(a, BwW[s * 64], acc, 0, 0, 0);
        }
        int o = wv * 16 + n;
        float bo = bias[o];
        // C/D: col = o, row m = q*4+reg = pixel -> w = w0 + q*4 + reg
        float4 st = {acc[0] + bo, acc[1] + bo, acc[2] + bo, acc[3] + bo};
        *(float4*)&out[(((size_t)b * 64 + o) * 128 + h) * 128 + w0 + q * 4] = st;
    }
}

// ---------------------------------------------------------------- launch
extern "C" void kernel_launch(void* const* d_in, const int* in_sizes, int n_in,
                              void* d_out, int out_size, void* d_ws, size_t ws_size,
                              hipStream_t stream) {
    const float* x        = (const float*)d_in[0];
    const float* offset_w = (const float*)d_in[1];
    const float* offset_b = (const float*)d_in[2];
    const float* weight   = (const float*)d_in[3];
    const float* bias     = (const float*)d_in[4];
    char* ws = (char*)d_ws;
    __hip_bfloat16* xBp = (__hip_bfloat16*)ws;                          // 8,652,800 B
    __hip_bfloat16* Wb  = (__hip_bfloat16*)(ws + 8652800);              // 73,728 B
    __hip_bfloat16* OWb = (__hip_bfloat16*)(ws + 8652800 + 73728);      // 36,864 B
    float* off_g        = (float*)(ws + 8652800 + 73728 + 36864);       // 4,718,592 B
    float* outp = (float*)d_out;

    hipLaunchKernelGGL(prep_kernel,      dim3(216),  dim3(256), 0, stream, offset_w, weight, Wb, OWb);
    hipLaunchKernelGGL(transpose_kernel, dim3(520),  dim3(256), 0, stream, x, xBp);
    hipLaunchKernelGGL(offconv_kernel,   dim3(1024), dim3(256), 0, stream, xBp, OWb, offset_b, off_g);
    hipLaunchKernelGGL(deform_kernel,    dim3(4096), dim3(256), 0, stream, xBp, Wb, off_g, bias, outp);
}

// Round 5
// 117.489 us; speedup vs baseline: 1.0243x; 1.0243x over previous
//
#include <hip/hip_runtime.h>
#include <hip/hip_bf16.h>

// B=4, C=64, O=64, H=W=128, K=3, KK=9, PAD=1
// MFMA 16x16x32 bf16: A[m=lane&15][k=(lane>>4)*8+j], B[n=lane&15][k=...],
// C/D: col(n)=lane&15, row(m)=(lane>>4)*4+reg
// kappa = s*32 + q*8 + j  ->  tap = s>>1, c = (s&1)*32 + q*8 + j
//
// XCD swizzle (8 XCDs, hw assigns XCD = blockIdx%8): bid=(blockIdx&7)*cpx+(blockIdx>>3)
// puts a contiguous (b,h)-slice on each XCD -> xBp slice ~1.06MB fits 4MiB XCD L2,
// and transpose/offconv/deform slices coincide (cross-kernel L2 warm).
//
// ws layout (bytes):
//   xBp  [4][130][130][64] bf16 : ofs 0        (8.65 MB zero-halo padded NHWC bf16 of x)
//   Wb   [4][18][64][8]   bf16  : ofs 8652800  (deform weight B-frags)
//   OWb  [2][18][64][8]   bf16  : ofs 8726528  (offset_w B-frags)
//   off_g[4][128][18][128] f32  : ofs 8763392  (offset-conv output, 4.72 MB)

typedef short short8 __attribute__((ext_vector_type(8)));
typedef short short4v __attribute__((ext_vector_type(4)));
typedef float f32x4 __attribute__((ext_vector_type(4)));

static __device__ inline short bf16s(float f) {
    __hip_bfloat16 h = __float2bfloat16(f);
    return *(short*)&h;
}
static __device__ inline float lo2f(unsigned u) { return __uint_as_float(u << 16); }
static __device__ inline float hi2f(unsigned u) { return __uint_as_float(u & 0xffff0000u); }

// ---------------------------------------------------------------- fused prep + NCHW->padded-NHWC-bf16
// grid = 736: blocks 0..519 transpose (XCD-swizzled), 520..735 prep fragment packing.
__global__ void prep_transpose_kernel(const float* __restrict__ x,
                                      __hip_bfloat16* __restrict__ xBp,
                                      const float* __restrict__ offset_w, // [18][64][9]
                                      const float* __restrict__ weight,   // [64][64][9]
                                      __hip_bfloat16* __restrict__ Wb,    // [4][18][64][8]
                                      __hip_bfloat16* __restrict__ OWb)   // [2][18][64][8]
{
    __shared__ __align__(16) float lds[128 * 65];
    int raw = blockIdx.x;
    int t = threadIdx.x;

    if (raw >= 520) {                   // ---- prep path
        int id = (raw - 520) * 256 + t;
        if (id < 36864) {
            int j    = id & 7;
            int lane = (id >> 3) & 63;
            int id3  = id >> 9;
            int s    = id3 % 18;
            int otile = id3 / 18;
            int n = lane & 15, q = lane >> 4;
            int kap = s * 32 + q * 8 + j;      // kappa = k*64 + c
            int k = kap >> 6, c = kap & 63;
            int o = otile * 16 + n;
            Wb[id] = __float2bfloat16(weight[(o * 64 + c) * 9 + k]);
        }
        int id2 = id - 36864;
        if (id2 >= 0 && id2 < 18432) {
            int j    = id2 & 7;
            int lane = (id2 >> 3) & 63;
            int id3  = id2 >> 9;
            int s    = id3 % 18;
            int ntile = id3 / 18;
            int n = lane & 15, q = lane >> 4;
            int kap = s * 32 + q * 8 + j;
            int k = kap >> 6, c = kap & 63;
            int o = ntile * 16 + n;
            float v = (o < 18) ? offset_w[(o * 64 + c) * 9 + k] : 0.0f;
            OWb[id2] = __float2bfloat16(v);
        }
        return;
    }

    // ---- transpose path (XCD swizzle: 520 = 8*65)
    int blk = (raw & 7) * 65 + (raw >> 3);   // b*130 + r
    int b = blk / 130, r = blk - b * 130;
    unsigned* rowp = (unsigned*)(xBp + (size_t)(b * 130 + r) * 130 * 64); // 4160 dwords per row
    if (r == 0 || r == 129) {           // full zero row (halo)
        uint4 z = {0u, 0u, 0u, 0u};
        for (int i = 0; i < 5; ++i) {
            int e = i * 256 + t;
            if (e < 1040) ((uint4*)rowp)[e] = z;
        }
        return;
    }
    int h = r - 1;
    int w = t & 127, chalf = t >> 7;
    for (int i = 0; i < 32; ++i) {
        int c = i * 2 + chalf;
        lds[w * 65 + c] = x[((b * 64 + c) * 128 + h) * 128 + w];
    }
    __syncthreads();
    unsigned* dst = rowp + 32;          // col 1 (each col = 64 shorts = 32 dwords)
    for (int i = 0; i < 16; ++i) {
        int L = i * 256 + t;            // L = ww*32 + c2
        int ww = L >> 5, c2 = L & 31;
        float f0 = lds[ww * 65 + c2 * 2];
        float f1 = lds[ww * 65 + c2 * 2 + 1];
        unsigned pk = ((unsigned)bf16s(f0) & 0xffffu) | ((unsigned)bf16s(f1) << 16);
        dst[L] = pk;
    }
    if (t < 64) {                       // zero halo cols 0 and 129
        int col = (t >> 5) * 129;
        rowp[col * 32 + (t & 31)] = 0u;
    }
}

// ---------------------------------------------------------------- standalone offset conv via MFMA
// grid = 4*128*2 (XCD-swizzled); block = 64 px of one row; 4 waves x 16 px.
// Writes off_g[b][h][o][w] f32 (o<18).
__global__ __launch_bounds__(256, 4) void offconv_kernel(
    const __hip_bfloat16* __restrict__ xBp, // [4][130][130][64]
    const __hip_bfloat16* __restrict__ OWb, // [2][18][64][8]
    const float* __restrict__ offset_b,     // [18]
    float* __restrict__ off_g)              // [4][128][18][128]
{
    __shared__ __align__(16) short patch[198 * 80];  // 3 rows x 66 cols, stride 80 shorts; 31680 B

    int t = threadIdx.x, wv = t >> 6, lane = t & 63;
    int bid = (blockIdx.x & 7) * 128 + (blockIdx.x >> 3);  // XCD swizzle (1024 = 8*128)
    int half = bid & 1;
    int bh = bid >> 1;
    int b = bh >> 7, h = bh & 127;
    int w0 = half * 64;

    // stage 198 px (padded rows h..h+2, padded cols w0..w0+65), no bounds checks (halo is zero)
    for (int i = 0; i < 7; ++i) {
        int e = i * 256 + t;            // 16-B chunk id; 198*8 = 1584 chunks
        if (e < 1584) {
            int px = e >> 3, part = e & 7;
            int prow = px / 66, pcol = px - prow * 66;
            const uint4* src = (const uint4*)(xBp +
                (size_t)((b * 130 + h + prow) * 130 + w0 + pcol) * 64 + part * 8);
            *(uint4*)&patch[px * 80 + part * 8] = *src;
        }
    }
    __syncthreads();

    int n = lane & 15, q = lane >> 4;
    const short8* Bw = (const short8*)OWb;   // [2][18][64]
    f32x4 acc0 = {0.f, 0.f, 0.f, 0.f};
    f32x4 acc1 = {0.f, 0.f, 0.f, 0.f};
#pragma unroll
    for (int s = 0; s < 18; ++s) {
        int k = s >> 1;
        int ky = k / 3, kx = k - ky * 3;
        int pix = ky * 66 + wv * 16 + n + kx;
        const short8 a = *(const short8*)&patch[pix * 80 + (s & 1) * 32 + q * 8];
        acc0 = __builtin_amdgcn_mfma_f32_16x16x32_bf16(a, Bw[(0 * 18 + s) * 64 + lane], acc0, 0, 0, 0);
        acc1 = __builtin_amdgcn_mfma_f32_16x16x32_bf16(a, Bw[(1 * 18 + s) * 64 + lane], acc1, 0, 0, 0);
    }
    // C/D: col = o = lane&15, rows = pixels q*4+r  -> float4 store along w
    float* og = off_g + ((size_t)(b * 128 + h) * 18) * 128 + w0 + wv * 16 + q * 4;
    {
        float bo = offset_b[n];
        float4 st = {acc0[0] + bo, acc0[1] + bo, acc0[2] + bo, acc0[3] + bo};
        *(float4*)&og[n * 128] = st;
    }
    if (n < 2) {
        int o = 16 + n;
        float bo = offset_b[o];
        float4 st = {acc1[0] + bo, acc1[1] + bo, acc1[2] + bo, acc1[3] + bo};
        *(float4*)&og[o * 128] = st;
    }
}

// ---------------------------------------------------------------- fused sampling + deformable conv
// block = 16x1 row tile; 4 waves; grid = 4096 (XCD-swizzled: 8*512)
// LDS = sampB 23040 + offL 1152 = 24192 B
__global__ __launch_bounds__(256, 6) void deform_kernel(
    const __hip_bfloat16* __restrict__ xBp, // [4][130][130][64] padded NHWC bf16
    const __hip_bfloat16* __restrict__ Wb,  // [4][18][64][8]
    const float* __restrict__ off_g,        // [4][128][18][128]
    const float* __restrict__ bias,         // [64]
    float* __restrict__ out)                // [4][64][128][128] NCHW
{
    __shared__ __align__(16) short sampB[18 * 16 * 40];  // 23040 B
    __shared__ __align__(16) float offL[288];            // [o][p]

    int t = threadIdx.x, wv = t >> 6, lane = t & 63;
    int bid = (blockIdx.x & 7) * 512 + (blockIdx.x >> 3); // XCD swizzle: contiguous (b,h) per XCD
    int b  = bid >> 10;
    int h  = (bid >> 3) & 127;
    int w0 = (bid & 7) << 4;

    // ---- phase 0: load this tile's 18x16 offsets (288 floats, strided over 256 threads)
    for (int e = t; e < 288; e += 256) {
        int o = e >> 4, p = e & 15;
        offL[o * 16 + p] = off_g[((size_t)((b * 128 + h) * 18 + o)) * 128 + w0 + p];
    }
    __syncthreads();

    // ---- phase 1: sampling; 16-lane group g owns pixel p=wv*4+g; lane c4 owns ch 4c4..4c4+3
    // Zero-halo padding: clamp coords to [-1,128]; halo reads return 0 == reference's valid-masking.
    {
        int g = lane >> 4, c4 = lane & 15;
        int p = wv * 4 + g;
        const __hip_bfloat16* xb4 = xBp + (size_t)b * (130 * 130 * 64) + c4 * 4 + 131 * 64;

        float offy[9], offx[9];
#pragma unroll
        for (int k = 0; k < 9; ++k) {
            offy[k] = offL[(2 * k) * 16 + p];
            offx[k] = offL[(2 * k + 1) * 16 + p];
        }

#pragma unroll
        for (int k = 0; k < 9; ++k) {
            float py = (float)(h - 1 + (k / 3)) + offy[k];
            float px = (float)(w0 + p - 1 + (k % 3)) + offx[k];
            float y0f = floorf(py), x0f = floorf(px);
            float wy1 = py - y0f, wx1 = px - x0f;
            float wy0 = 1.0f - wy1, wx0 = 1.0f - wx1;
            int iy = (int)y0f, ix = (int)x0f;
            int iy0 = min(max(iy, -1), 128);
            int ix0 = min(max(ix, -1), 128);
            int iy1 = min(max(iy + 1, -1), 128);
            int ix1 = min(max(ix + 1, -1), 128);
            int rb0 = iy0 * 130, rb1 = iy1 * 130;
            int e00 = (rb0 + ix0) * 64;
            int e01 = (rb0 + ix1) * 64;
            int e10 = (rb1 + ix0) * 64;
            int e11 = (rb1 + ix1) * 64;
            float wa  = wy0 * wx0;
            float wb_ = wy0 * wx1;
            float wc  = wy1 * wx0;
            float wd  = wy1 * wx1;

            uint2 r0 = *(const uint2*)(xb4 + e00);
            uint2 r1 = *(const uint2*)(xb4 + e01);
            uint2 r2 = *(const uint2*)(xb4 + e10);
            uint2 r3 = *(const uint2*)(xb4 + e11);

            float s0 = fmaf(wd, lo2f(r3.x), fmaf(wc, lo2f(r2.x), fmaf(wb_, lo2f(r1.x), wa * lo2f(r0.x))));
            float s1 = fmaf(wd, hi2f(r3.x), fmaf(wc, hi2f(r2.x), fmaf(wb_, hi2f(r1.x), wa * hi2f(r0.x))));
            float s2 = fmaf(wd, lo2f(r3.y), fmaf(wc, lo2f(r2.y), fmaf(wb_, lo2f(r1.y), wa * lo2f(r0.y))));
            float s3 = fmaf(wd, hi2f(r3.y), fmaf(wc, hi2f(r2.y), fmaf(wb_, hi2f(r1.y), wa * hi2f(r0.y))));
            int s = 2 * k + (c4 >> 3);
            short4v pk = { bf16s(s0), bf16s(s1), bf16s(s2), bf16s(s3) };
            *(short4v*)&sampB[(s * 16 + p) * 40 + (c4 & 7) * 4] = pk;
        }
    }
    __syncthreads();

    // ---- phase 2: einsum via MFMA; wave wv = o-tile; 18 K-steps
    {
        int n = lane & 15, q = lane >> 4;
        int arow = n * 40 + q * 8;          // A: m = pixel = lane&15
        const short8* BwW = (const short8*)Wb + (wv * 18) * 64 + lane;
        f32x4 acc = {0.f, 0.f, 0.f, 0.f};
#pragma unroll
        for (int s = 0; s < 18; ++s) {
            const short8 a = *(const short8*)&sampB[s * 640 + arow];
            acc = __builtin_amdgcn_mfma_f32_16x16x32_bf16(a, BwW[s * 64], acc, 0, 0, 0);
        }
        int o = wv * 16 + n;
        float bo = bias[o];
        // C/D: col = o, row m = q*4+reg = pixel -> w = w0 + q*4 + reg
        float4 st = {acc[0] + bo, acc[1] + bo, acc[2] + bo, acc[3] + bo};
        *(float4*)&out[(((size_t)b * 64 + o) * 128 + h) * 128 + w0 + q * 4] = st;
    }
}

// ---------------------------------------------------------------- launch
extern "C" void kernel_launch(void* const* d_in, const int* in_sizes, int n_in,
                              void* d_out, int out_size, void* d_ws, size_t ws_size,
                              hipStream_t stream) {
    const float* x        = (const float*)d_in[0];
    const float* offset_w = (const float*)d_in[1];
    const float* offset_b = (const float*)d_in[2];
    const float* weight   = (const float*)d_in[3];
    const float* bias     = (const float*)d_in[4];
    char* ws = (char*)d_ws;
    __hip_bfloat16* xBp = (__hip_bfloat16*)ws;                          // 8,652,800 B
    __hip_bfloat16* Wb  = (__hip_bfloat16*)(ws + 8652800);              // 73,728 B
    __hip_bfloat16* OWb = (__hip_bfloat16*)(ws + 8652800 + 73728);      // 36,864 B
    float* off_g        = (float*)(ws + 8652800 + 73728 + 36864);       // 4,718,592 B
    float* outp = (float*)d_out;

    hipLaunchKernelGGL(prep_transpose_kernel, dim3(736),  dim3(256), 0, stream,
                       x, xBp, offset_w, weight, Wb, OWb);
    hipLaunchKernelGGL(offconv_kernel,        dim3(1024), dim3(256), 0, stream, xBp, OWb, offset_b, off_g);
    hipLaunchKernelGGL(deform_kernel,         dim3(4096), dim3(256), 0, stream, xBp, Wb, off_g, bias, outp);
}

// Round 7
// 111.827 us; speedup vs baseline: 1.0761x; 1.0506x over previous
//
#include <hip/hip_runtime.h>
#include <hip/hip_bf16.h>

// B=4, C=64, O=64, H=W=128, K=3, KK=9, PAD=1
// MFMA 16x16x32 bf16: A[m=lane&15][k=(lane>>4)*8+j], B[n=lane&15][k=...],
// C/D: col(n)=lane&15, row(m)=(lane>>4)*4+reg
// kappa = s*32 + q*8 + j  ->  tap = s>>1, c = (s&1)*32 + q*8 + j
//
// Fused round-0 structure (in-block offconv; measured best) + zero-halo padded xBp
// (branchless staging/sampling) + XCD swizzle (contiguous (b,h) slice per XCD) +
// prep folded into transpose launch (2 launches total).
//
// ws layout (bytes):
//   xBp  [4][130][130][64] bf16 : ofs 0        (8.65 MB zero-halo padded NHWC bf16 of x)
//   Wb   [4][18][64][8]   bf16  : ofs 8652800  (deform weight B-frags)
//   OWb  [2][18][64][8]   bf16  : ofs 8726528  (offset_w B-frags)

typedef short short8 __attribute__((ext_vector_type(8)));
typedef short short4v __attribute__((ext_vector_type(4)));
typedef float f32x4 __attribute__((ext_vector_type(4)));

static __device__ inline short bf16s(float f) {
    __hip_bfloat16 h = __float2bfloat16(f);
    return *(short*)&h;
}
static __device__ inline float lo2f(unsigned u) { return __uint_as_float(u << 16); }
static __device__ inline float hi2f(unsigned u) { return __uint_as_float(u & 0xffff0000u); }

// ---------------------------------------------------------------- fused prep + NCHW->padded-NHWC-bf16
// grid = 736: blocks 0..519 transpose (XCD-swizzled), 520..735 prep fragment packing.
__global__ void prep_transpose_kernel(const float* __restrict__ x,
                                      __hip_bfloat16* __restrict__ xBp,
                                      const float* __restrict__ offset_w, // [18][64][9]
                                      const float* __restrict__ weight,   // [64][64][9]
                                      __hip_bfloat16* __restrict__ Wb,    // [4][18][64][8]
                                      __hip_bfloat16* __restrict__ OWb)   // [2][18][64][8]
{
    __shared__ __align__(16) float lds[128 * 65];
    int raw = blockIdx.x;
    int t = threadIdx.x;

    if (raw >= 520) {                   // ---- prep path
        int id = (raw - 520) * 256 + t;
        if (id < 36864) {
            int j    = id & 7;
            int lane = (id >> 3) & 63;
            int id3  = id >> 9;
            int s    = id3 % 18;
            int otile = id3 / 18;
            int n = lane & 15, q = lane >> 4;
            int kap = s * 32 + q * 8 + j;      // kappa = k*64 + c
            int k = kap >> 6, c = kap & 63;
            int o = otile * 16 + n;
            Wb[id] = __float2bfloat16(weight[(o * 64 + c) * 9 + k]);
        }
        int id2 = id - 36864;
        if (id2 >= 0 && id2 < 18432) {
            int j    = id2 & 7;
            int lane = (id2 >> 3) & 63;
            int id3  = id2 >> 9;
            int s    = id3 % 18;
            int ntile = id3 / 18;
            int n = lane & 15, q = lane >> 4;
            int kap = s * 32 + q * 8 + j;
            int k = kap >> 6, c = kap & 63;
            int o = ntile * 16 + n;
            float v = (o < 18) ? offset_w[(o * 64 + c) * 9 + k] : 0.0f;
            OWb[id2] = __float2bfloat16(v);
        }
        return;
    }

    // ---- transpose path (XCD swizzle: 520 = 8*65)
    int blk = (raw & 7) * 65 + (raw >> 3);   // b*130 + r
    int b = blk / 130, r = blk - b * 130;
    unsigned* rowp = (unsigned*)(xBp + (size_t)(b * 130 + r) * 130 * 64); // 4160 dwords per row
    if (r == 0 || r == 129) {           // full zero row (halo)
        uint4 z = {0u, 0u, 0u, 0u};
        for (int i = 0; i < 5; ++i) {
            int e = i * 256 + t;
            if (e < 1040) ((uint4*)rowp)[e] = z;
        }
        return;
    }
    int h = r - 1;
    int w = t & 127, chalf = t >> 7;
    for (int i = 0; i < 32; ++i) {
        int c = i * 2 + chalf;
        lds[w * 65 + c] = x[((b * 64 + c) * 128 + h) * 128 + w];
    }
    __syncthreads();
    unsigned* dst = rowp + 32;          // col 1 (each col = 64 shorts = 32 dwords)
    for (int i = 0; i < 16; ++i) {
        int L = i * 256 + t;            // L = ww*32 + c2
        int ww = L >> 5, c2 = L & 31;
        float f0 = lds[ww * 65 + c2 * 2];
        float f1 = lds[ww * 65 + c2 * 2 + 1];
        unsigned pk = ((unsigned)bf16s(f0) & 0xffffu) | ((unsigned)bf16s(f1) << 16);
        dst[L] = pk;
    }
    if (t < 64) {                       // zero halo cols 0 and 129
        int col = (t >> 5) * 129;
        rowp[col * 32 + (t & 31)] = 0u;
    }
}

// ---------------------------------------------------------------- fused offconv + sampling + deform conv
// block = 16x1 row tile; 4 waves; grid = 4096 (XCD-swizzled: 8*512)
// LDS = sampB 23040 (patch[54][80] aliases its head) + offL 1152 = 24192 B -> 6 blocks/CU
__global__ __launch_bounds__(256, 6) void deform_kernel(
    const __hip_bfloat16* __restrict__ xBp, // [4][130][130][64] padded NHWC bf16
    const __hip_bfloat16* __restrict__ Wb,  // [4][18][64][8]
    const __hip_bfloat16* __restrict__ OWb, // [2][18][64][8]
    const float* __restrict__ offset_b,     // [18]
    const float* __restrict__ bias,         // [64]
    float* __restrict__ out)                // [4][64][128][128] NCHW
{
    __shared__ __align__(16) short sampB[18 * 16 * 40];  // 23040 B
    __shared__ __align__(16) float offL[288];            // [o][p] (separate — NOT aliased)

    int t = threadIdx.x, wv = t >> 6, lane = t & 63;
    int bid = (blockIdx.x & 7) * 512 + (blockIdx.x >> 3); // XCD swizzle: contiguous (b,h) per XCD
    int b  = bid >> 10;
    int h  = (bid >> 3) & 127;
    int w0 = (bid & 7) << 4;

    short* patch = sampB;            // [54 px][80 shorts]; px = row*18+col
                                     // rows = padded h..h+2 (unpadded h-1..h+1),
                                     // cols = padded w0..w0+17 (unpadded w0-1..w0+16)

    // ---- phase 1: stage 3x18x64 patch bf16 — branchless (halo is pre-zeroed), 16-B chunks
    {
#pragma unroll
        for (int i = 0; i < 2; ++i) {
            int e = i * 256 + t;            // 54*8 = 432 chunks of 16 B
            if (e < 432) {
                int px = e >> 3, part = e & 7;
                int row = px / 18, col = px - row * 18;
                const uint4* src = (const uint4*)(xBp +
                    ((size_t)((b * 130 + h + row) * 130) + w0 + col) * 64 + part * 8);
                *(uint4*)&patch[px * 80 + part * 8] = *src;
            }
        }
    }
    __syncthreads();

    // ---- phase 2: offset conv via MFMA (waves 0,1; o = wv*16+n; pixel p = q*4+reg)
    if (wv < 2) {
        int n = lane & 15, q = lane >> 4;
        const short8* Bw = (const short8*)OWb + (wv * 18) * 64 + lane;
        f32x4 acc = {0.f, 0.f, 0.f, 0.f};
#pragma unroll
        for (int s = 0; s < 18; ++s) {
            int k = s >> 1;
            int ky = k / 3, kx = k - ky * 3;
            int pix = ky * 18 + n + kx;
            const short8 a = *(const short8*)&patch[pix * 80 + (s & 1) * 32 + q * 8];
            acc = __builtin_amdgcn_mfma_f32_16x16x32_bf16(a, Bw[s * 64], acc, 0, 0, 0);
        }
        int o = wv * 16 + n;
        if (o < 18) {
            float bo = offset_b[o];
#pragma unroll
            for (int r = 0; r < 4; ++r)
                offL[o * 16 + q * 4 + r] = acc[r] + bo;
        }
    }
    __syncthreads();

    // ---- phase 4: sampling; 16-lane group g owns pixel p=wv*4+g; lane c4 owns ch 4c4..4c4+3
    // Zero-halo padding: clamp coords to [-1,128]; halo reads return 0 == reference's valid-masking.
    // (sampB overwrites patch — safe: patch last read in phase 2, barrier between.)
    {
        int g = lane >> 4, c4 = lane & 15;
        int p = wv * 4 + g;
        const __hip_bfloat16* xb4 = xBp + (size_t)b * (130 * 130 * 64) + c4 * 4 + 131 * 64;

        float offy[9], offx[9];
#pragma unroll
        for (int k = 0; k < 9; ++k) {
            offy[k] = offL[(2 * k) * 16 + p];
            offx[k] = offL[(2 * k + 1) * 16 + p];
        }

#pragma unroll
        for (int k = 0; k < 9; ++k) {
            float py = (float)(h - 1 + (k / 3)) + offy[k];
            float px = (float)(w0 + p - 1 + (k % 3)) + offx[k];
            float y0f = floorf(py), x0f = floorf(px);
            float wy1 = py - y0f, wx1 = px - x0f;
            float wy0 = 1.0f - wy1, wx0 = 1.0f - wx1;
            int iy = (int)y0f, ix = (int)x0f;
            int iy0 = min(max(iy, -1), 128);
            int ix0 = min(max(ix, -1), 128);
            int iy1 = min(max(iy + 1, -1), 128);
            int ix1 = min(max(ix + 1, -1), 128);
            int rb0 = iy0 * 130, rb1 = iy1 * 130;
            int e00 = (rb0 + ix0) * 64;
            int e01 = (rb0 + ix1) * 64;
            int e10 = (rb1 + ix0) * 64;
            int e11 = (rb1 + ix1) * 64;
            float wa  = wy0 * wx0;
            float wb_ = wy0 * wx1;
            float wc  = wy1 * wx0;
            float wd  = wy1 * wx1;

            uint2 r0 = *(const uint2*)(xb4 + e00);
            uint2 r1 = *(const uint2*)(xb4 + e01);
            uint2 r2 = *(const uint2*)(xb4 + e10);
            uint2 r3 = *(const uint2*)(xb4 + e11);

            float s0 = fmaf(wd, lo2f(r3.x), fmaf(wc, lo2f(r2.x), fmaf(wb_, lo2f(r1.x), wa * lo2f(r0.x))));
            float s1 = fmaf(wd, hi2f(r3.x), fmaf(wc, hi2f(r2.x), fmaf(wb_, hi2f(r1.x), wa * hi2f(r0.x))));
            float s2 = fmaf(wd, lo2f(r3.y), fmaf(wc, lo2f(r2.y), fmaf(wb_, lo2f(r1.y), wa * lo2f(r0.y))));
            float s3 = fmaf(wd, hi2f(r3.y), fmaf(wc, hi2f(r2.y), fmaf(wb_, hi2f(r1.y), wa * hi2f(r0.y))));
            int s = 2 * k + (c4 >> 3);
            short4v pk = { bf16s(s0), bf16s(s1), bf16s(s2), bf16s(s3) };
            *(short4v*)&sampB[(s * 16 + p) * 40 + (c4 & 7) * 4] = pk;
        }
    }
    __syncthreads();

    // ---- phase 5: einsum via MFMA; wave wv = o-tile; 18 K-steps
    {
        int n = lane & 15, q = lane >> 4;
        int arow = n * 40 + q * 8;          // A: m = pixel = lane&15
        const short8* BwW = (const short8*)Wb + (wv * 18) * 64 + lane;
        f32x4 acc = {0.f, 0.f, 0.f, 0.f};
#pragma unroll
        for (int s = 0; s < 18; ++s) {
            const short8 a = *(const short8*)&sampB[s * 640 + arow];
            acc = __builtin_amdgcn_mfma_f32_16x16x32_bf16(a, BwW[s * 64], acc, 0, 0, 0);
        }
        int o = wv * 16 + n;
        float bo = bias[o];
        // C/D: col = o, row m = q*4+reg = pixel -> w = w0 + q*4 + reg
        float4 st = {acc[0] + bo, acc[1] + bo, acc[2] + bo, acc[3] + bo};
        *(float4*)&out[(((size_t)b * 64 + o) * 128 + h) * 128 + w0 + q * 4] = st;
    }
}

// ---------------------------------------------------------------- launch
extern "C" void kernel_launch(void* const* d_in, const int* in_sizes, int n_in,
                              void* d_out, int out_size, void* d_ws, size_t ws_size,
                              hipStream_t stream) {
    const float* x        = (const float*)d_in[0];
    const float* offset_w = (const float*)d_in[1];
    const float* offset_b = (const float*)d_in[2];
    const float* weight   = (const float*)d_in[3];
    const float* bias     = (const float*)d_in[4];
    char* ws = (char*)d_ws;
    __hip_bfloat16* xBp = (__hip_bfloat16*)ws;                          // 8,652,800 B
    __hip_bfloat16* Wb  = (__hip_bfloat16*)(ws + 8652800);              // 73,728 B
    __hip_bfloat16* OWb = (__hip_bfloat16*)(ws + 8652800 + 73728);      // 36,864 B
    float* outp = (float*)d_out;

    hipLaunchKernelGGL(prep_transpose_kernel, dim3(736),  dim3(256), 0, stream,
                       x, xBp, offset_w, weight, Wb, OWb);
    hipLaunchKernelGGL(deform_kernel,         dim3(4096), dim3(256), 0, stream,
                       xBp, Wb, OWb, offset_b, bias, outp);
}

// Round 8
// 109.377 us; speedup vs baseline: 1.1002x; 1.0224x over previous
//
#include <hip/hip_runtime.h>
#include <hip/hip_bf16.h>

// B=4, C=64, O=64, H=W=128, K=3, KK=9, PAD=1
// MFMA 16x16x32 bf16: A[m=lane&15][k=(lane>>4)*8+j], B[n=lane&15][k=...],
// C/D: col(n)=lane&15, row(m)=(lane>>4)*4+reg
// kappa = s*32 + q*8 + j  ->  tap = s>>1, c = (s&1)*32 + q*8 + j
//
// Fused structure + padded xBp + XCD swizzle (round-7: 111.8 µs, deform 44.6 µs).
// Round-8 change: phase-4 sampling re-partition — 8 lanes/pixel, uint4 (16-B) corner
// loads, taps split across wave pairs (wv<2: k0..3, wv>=2: k4..8). Halves per-lane
// load count + VALU, doubles bytes/load -> more bytes in flight at same VGPR budget
// (round-7 counters: VGPR=40 => ~5 loads in flight vs 200-cyc L2 latency = stall-bound).
//
// ws layout (bytes):
//   xBp  [4][130][130][64] bf16 : ofs 0        (8.65 MB zero-halo padded NHWC bf16 of x)
//   Wb   [4][18][64][8]   bf16  : ofs 8652800  (deform weight B-frags)
//   OWb  [2][18][64][8]   bf16  : ofs 8726528  (offset_w B-frags)

typedef short short8 __attribute__((ext_vector_type(8)));
typedef float f32x4 __attribute__((ext_vector_type(4)));

static __device__ inline short bf16s(float f) {
    __hip_bfloat16 h = __float2bfloat16(f);
    return *(short*)&h;
}
static __device__ inline float lo2f(unsigned u) { return __uint_as_float(u << 16); }
static __device__ inline float hi2f(unsigned u) { return __uint_as_float(u & 0xffff0000u); }

// ---------------------------------------------------------------- fused prep + NCHW->padded-NHWC-bf16
// grid = 736: blocks 0..519 transpose (XCD-swizzled), 520..735 prep fragment packing.
__global__ void prep_transpose_kernel(const float* __restrict__ x,
                                      __hip_bfloat16* __restrict__ xBp,
                                      const float* __restrict__ offset_w, // [18][64][9]
                                      const float* __restrict__ weight,   // [64][64][9]
                                      __hip_bfloat16* __restrict__ Wb,    // [4][18][64][8]
                                      __hip_bfloat16* __restrict__ OWb)   // [2][18][64][8]
{
    __shared__ __align__(16) float lds[128 * 65];
    int raw = blockIdx.x;
    int t = threadIdx.x;

    if (raw >= 520) {                   // ---- prep path
        int id = (raw - 520) * 256 + t;
        if (id < 36864) {
            int j    = id & 7;
            int lane = (id >> 3) & 63;
            int id3  = id >> 9;
            int s    = id3 % 18;
            int otile = id3 / 18;
            int n = lane & 15, q = lane >> 4;
            int kap = s * 32 + q * 8 + j;      // kappa = k*64 + c
            int k = kap >> 6, c = kap & 63;
            int o = otile * 16 + n;
            Wb[id] = __float2bfloat16(weight[(o * 64 + c) * 9 + k]);
        }
        int id2 = id - 36864;
        if (id2 >= 0 && id2 < 18432) {
            int j    = id2 & 7;
            int lane = (id2 >> 3) & 63;
            int id3  = id2 >> 9;
            int s    = id3 % 18;
            int ntile = id3 / 18;
            int n = lane & 15, q = lane >> 4;
            int kap = s * 32 + q * 8 + j;
            int k = kap >> 6, c = kap & 63;
            int o = ntile * 16 + n;
            float v = (o < 18) ? offset_w[(o * 64 + c) * 9 + k] : 0.0f;
            OWb[id2] = __float2bfloat16(v);
        }
        return;
    }

    // ---- transpose path (XCD swizzle: 520 = 8*65)
    int blk = (raw & 7) * 65 + (raw >> 3);   // b*130 + r
    int b = blk / 130, r = blk - b * 130;
    unsigned* rowp = (unsigned*)(xBp + (size_t)(b * 130 + r) * 130 * 64); // 4160 dwords per row
    if (r == 0 || r == 129) {           // full zero row (halo)
        uint4 z = {0u, 0u, 0u, 0u};
        for (int i = 0; i < 5; ++i) {
            int e = i * 256 + t;
            if (e < 1040) ((uint4*)rowp)[e] = z;
        }
        return;
    }
    int h = r - 1;
    int w = t & 127, chalf = t >> 7;
    for (int i = 0; i < 32; ++i) {
        int c = i * 2 + chalf;
        lds[w * 65 + c] = x[((b * 64 + c) * 128 + h) * 128 + w];
    }
    __syncthreads();
    unsigned* dst = rowp + 32;          // col 1 (each col = 64 shorts = 32 dwords)
    for (int i = 0; i < 16; ++i) {
        int L = i * 256 + t;            // L = ww*32 + c2
        int ww = L >> 5, c2 = L & 31;
        float f0 = lds[ww * 65 + c2 * 2];
        float f1 = lds[ww * 65 + c2 * 2 + 1];
        unsigned pk = ((unsigned)bf16s(f0) & 0xffffu) | ((unsigned)bf16s(f1) << 16);
        dst[L] = pk;
    }
    if (t < 64) {                       // zero halo cols 0 and 129
        int col = (t >> 5) * 129;
        rowp[col * 32 + (t & 31)] = 0u;
    }
}

// ---------------------------------------------------------------- phase-4 sampling helper
// Lane owns 8 channels (c8*8..c8*8+7) of pixel p; taps K0..K1-1.
// Zero-halo padding: clamp coords to [-1,128]; halo reads return 0 == valid-masking.
template<int K0, int K1>
static __device__ inline void sample_taps(const __hip_bfloat16* __restrict__ xb8,
                                          const float* __restrict__ offL,
                                          short* __restrict__ sampB,
                                          int h, int w0, int p, int c8)
{
    constexpr int NT = K1 - K0;
    float offy[NT], offx[NT];
#pragma unroll
    for (int i = 0; i < NT; ++i) {
        offy[i] = offL[(2 * (K0 + i)) * 16 + p];
        offx[i] = offL[(2 * (K0 + i) + 1) * 16 + p];
    }
#pragma unroll
    for (int i = 0; i < NT; ++i) {
        int k = K0 + i;
        float py = (float)(h - 1 + (k / 3)) + offy[i];
        float px = (float)(w0 + p - 1 + (k % 3)) + offx[i];
        float y0f = floorf(py), x0f = floorf(px);
        float wy1 = py - y0f, wx1 = px - x0f;
        float wy0 = 1.0f - wy1, wx0 = 1.0f - wx1;
        int iy = (int)y0f, ix = (int)x0f;
        int iy0 = min(max(iy, -1), 128);
        int ix0 = min(max(ix, -1), 128);
        int iy1 = min(max(iy + 1, -1), 128);
        int ix1 = min(max(ix + 1, -1), 128);
        int rb0 = iy0 * 130, rb1 = iy1 * 130;

        uint4 r0 = *(const uint4*)(xb8 + (rb0 + ix0) * 64);
        uint4 r1 = *(const uint4*)(xb8 + (rb0 + ix1) * 64);
        uint4 r2 = *(const uint4*)(xb8 + (rb1 + ix0) * 64);
        uint4 r3 = *(const uint4*)(xb8 + (rb1 + ix1) * 64);

        float wa  = wy0 * wx0;
        float wb_ = wy0 * wx1;
        float wc  = wy1 * wx0;
        float wd  = wy1 * wx1;

        short8 pk;
#define SAMP1(idx, comp, EXT) { \
            float sv = fmaf(wd, EXT(r3.comp), fmaf(wc, EXT(r2.comp), \
                       fmaf(wb_, EXT(r1.comp), wa * EXT(r0.comp)))); \
            pk[idx] = bf16s(sv); }
        SAMP1(0, x, lo2f) SAMP1(1, x, hi2f)
        SAMP1(2, y, lo2f) SAMP1(3, y, hi2f)
        SAMP1(4, z, lo2f) SAMP1(5, z, hi2f)
        SAMP1(6, w, lo2f) SAMP1(7, w, hi2f)
#undef SAMP1
        int s = 2 * k + (c8 >> 2);
        *(short8*)&sampB[(s * 16 + p) * 40 + (c8 & 3) * 8] = pk;
    }
}

// ---------------------------------------------------------------- fused offconv + sampling + deform conv
// block = 16x1 row tile; 4 waves; grid = 4096 (XCD-swizzled: 8*512)
// LDS = sampB 23040 (patch[54][80] aliases its head) + offL 1152 = 24192 B -> 6 blocks/CU
__global__ __launch_bounds__(256, 6) void deform_kernel(
    const __hip_bfloat16* __restrict__ xBp, // [4][130][130][64] padded NHWC bf16
    const __hip_bfloat16* __restrict__ Wb,  // [4][18][64][8]
    const __hip_bfloat16* __restrict__ OWb, // [2][18][64][8]
    const float* __restrict__ offset_b,     // [18]
    const float* __restrict__ bias,         // [64]
    float* __restrict__ out)                // [4][64][128][128] NCHW
{
    __shared__ __align__(16) short sampB[18 * 16 * 40];  // 23040 B
    __shared__ __align__(16) float offL[288];            // [o][p] (separate — NOT aliased)

    int t = threadIdx.x, wv = t >> 6, lane = t & 63;
    int bid = (blockIdx.x & 7) * 512 + (blockIdx.x >> 3); // XCD swizzle: contiguous (b,h) per XCD
    int b  = bid >> 10;
    int h  = (bid >> 3) & 127;
    int w0 = (bid & 7) << 4;

    short* patch = sampB;            // [54 px][80 shorts]; px = row*18+col
                                     // rows = padded h..h+2, cols = padded w0..w0+17

    // ---- phase 1: stage 3x18x64 patch bf16 — branchless (halo is pre-zeroed), 16-B chunks
    {
#pragma unroll
        for (int i = 0; i < 2; ++i) {
            int e = i * 256 + t;            // 54*8 = 432 chunks of 16 B
            if (e < 432) {
                int px = e >> 3, part = e & 7;
                int row = px / 18, col = px - row * 18;
                const uint4* src = (const uint4*)(xBp +
                    ((size_t)((b * 130 + h + row) * 130) + w0 + col) * 64 + part * 8);
                *(uint4*)&patch[px * 80 + part * 8] = *src;
            }
        }
    }
    __syncthreads();

    // ---- phase 2: offset conv via MFMA (waves 0,1; o = wv*16+n; pixel p = q*4+reg)
    if (wv < 2) {
        int n = lane & 15, q = lane >> 4;
        const short8* Bw = (const short8*)OWb + (wv * 18) * 64 + lane;
        f32x4 acc = {0.f, 0.f, 0.f, 0.f};
#pragma unroll
        for (int s = 0; s < 18; ++s) {
            int k = s >> 1;
            int ky = k / 3, kx = k - ky * 3;
            int pix = ky * 18 + n + kx;
            const short8 a = *(const short8*)&patch[pix * 80 + (s & 1) * 32 + q * 8];
            acc = __builtin_amdgcn_mfma_f32_16x16x32_bf16(a, Bw[s * 64], acc, 0, 0, 0);
        }
        int o = wv * 16 + n;
        if (o < 18) {
            float bo = offset_b[o];
#pragma unroll
            for (int r = 0; r < 4; ++r)
                offL[o * 16 + q * 4 + r] = acc[r] + bo;
        }
    }
    __syncthreads();

    // ---- phase 4: sampling; 8 lanes/pixel (lane owns 8 channels), taps split over wave pairs
    // waves 0,1: taps 0..3; waves 2,3: taps 4..8. p = (wv&1)*8 + (lane>>3).
    // (sampB overwrites patch — safe: patch last read in phase 2, barrier between.)
    {
        int g8 = lane >> 3, c8 = lane & 7;
        int p = (wv & 1) * 8 + g8;
        const __hip_bfloat16* xb8 = xBp + (size_t)b * (130 * 130 * 64) + c8 * 8 + 131 * 64;
        if (wv < 2) sample_taps<0, 4>(xb8, offL, sampB, h, w0, p, c8);
        else        sample_taps<4, 9>(xb8, offL, sampB, h, w0, p, c8);
    }
    __syncthreads();

    // ---- phase 5: einsum via MFMA; wave wv = o-tile; 18 K-steps
    {
        int n = lane & 15, q = lane >> 4;
        int arow = n * 40 + q * 8;          // A: m = pixel = lane&15
        const short8* BwW = (const short8*)Wb + (wv * 18) * 64 + lane;
        f32x4 acc = {0.f, 0.f, 0.f, 0.f};
#pragma unroll
        for (int s = 0; s < 18; ++s) {
            const short8 a = *(const short8*)&sampB[s * 640 + arow];
            acc = __builtin_amdgcn_mfma_f32_16x16x32_bf16(a, BwW[s * 64], acc, 0, 0, 0);
        }
        int o = wv * 16 + n;
        float bo = bias[o];
        // C/D: col = o, row m = q*4+reg = pixel -> w = w0 + q*4 + reg
        float4 st = {acc[0] + bo, acc[1] + bo, acc[2] + bo, acc[3] + bo};
        *(float4*)&out[(((size_t)b * 64 + o) * 128 + h) * 128 + w0 + q * 4] = st;
    }
}

// ---------------------------------------------------------------- launch
extern "C" void kernel_launch(void* const* d_in, const int* in_sizes, int n_in,
                              void* d_out, int out_size, void* d_ws, size_t ws_size,
                              hipStream_t stream) {
    const float* x        = (const float*)d_in[0];
    const float* offset_w = (const float*)d_in[1];
    const float* offset_b = (const float*)d_in[2];
    const float* weight   = (const float*)d_in[3];
    const float* bias     = (const float*)d_in[4];
    char* ws = (char*)d_ws;
    __hip_bfloat16* xBp = (__hip_bfloat16*)ws;                          // 8,652,800 B
    __hip_bfloat16* Wb  = (__hip_bfloat16*)(ws + 8652800);              // 73,728 B
    __hip_bfloat16* OWb = (__hip_bfloat16*)(ws + 8652800 + 73728);      // 36,864 B
    float* outp = (float*)d_out;

    hipLaunchKernelGGL(prep_transpose_kernel, dim3(736),  dim3(256), 0, stream,
                       x, xBp, offset_w, weight, Wb, OWb);
    hipLaunchKernelGGL(deform_kernel,         dim3(4096), dim3(256), 0, stream,
                       xBp, Wb, OWb, offset_b, bias, outp);
}

// Round 9
// 105.674 us; speedup vs baseline: 1.1388x; 1.0350x over previous
//
#include <hip/hip_runtime.h>
#include <hip/hip_bf16.h>

// B=4, C=64, O=64, H=W=128, K=3, KK=9, PAD=1
// MFMA 16x16x32 bf16: A[m=lane&15][k=(lane>>4)*8+j], B[n=lane&15][k=...],
// C/D: col(n)=lane&15, row(m)=(lane>>4)*4+reg
// kappa = s*32 + q*8 + j  ->  tap = s>>1, c = (s&1)*32 + q*8 + j
//
// Round-9: phase-4 gather restructured as load-batch (all corner loads issued
// before any FMA; statically-indexed reg arrays) + launch_bounds 6->4
// (VGPR cap 85->128 so the whole tap batch fits in flight).
// Round-7 evidence: VGPR=40, MfmaUtil 6%, VALUBusy 35%, HBM 6% => latency-bound
// gather with ~5 loads in flight vs ~200-cyc L2 hit latency.
//
// ws layout (bytes):
//   xBp  [4][130][130][64] bf16 : ofs 0        (8.65 MB zero-halo padded NHWC bf16 of x)
//   Wb   [4][18][64][8]   bf16  : ofs 8652800  (deform weight B-frags)
//   OWb  [2][18][64][8]   bf16  : ofs 8726528  (offset_w B-frags)

typedef short short8 __attribute__((ext_vector_type(8)));
typedef float f32x4 __attribute__((ext_vector_type(4)));

static __device__ inline short bf16s(float f) {
    __hip_bfloat16 h = __float2bfloat16(f);
    return *(short*)&h;
}
static __device__ inline float lo2f(unsigned u) { return __uint_as_float(u << 16); }
static __device__ inline float hi2f(unsigned u) { return __uint_as_float(u & 0xffff0000u); }

// ---------------------------------------------------------------- fused prep + NCHW->padded-NHWC-bf16
// grid = 736: blocks 0..519 transpose (XCD-swizzled), 520..735 prep fragment packing.
__global__ void prep_transpose_kernel(const float* __restrict__ x,
                                      __hip_bfloat16* __restrict__ xBp,
                                      const float* __restrict__ offset_w, // [18][64][9]
                                      const float* __restrict__ weight,   // [64][64][9]
                                      __hip_bfloat16* __restrict__ Wb,    // [4][18][64][8]
                                      __hip_bfloat16* __restrict__ OWb)   // [2][18][64][8]
{
    __shared__ __align__(16) float lds[128 * 65];
    int raw = blockIdx.x;
    int t = threadIdx.x;

    if (raw >= 520) {                   // ---- prep path
        int id = (raw - 520) * 256 + t;
        if (id < 36864) {
            int j    = id & 7;
            int lane = (id >> 3) & 63;
            int id3  = id >> 9;
            int s    = id3 % 18;
            int otile = id3 / 18;
            int n = lane & 15, q = lane >> 4;
            int kap = s * 32 + q * 8 + j;      // kappa = k*64 + c
            int k = kap >> 6, c = kap & 63;
            int o = otile * 16 + n;
            Wb[id] = __float2bfloat16(weight[(o * 64 + c) * 9 + k]);
        }
        int id2 = id - 36864;
        if (id2 >= 0 && id2 < 18432) {
            int j    = id2 & 7;
            int lane = (id2 >> 3) & 63;
            int id3  = id2 >> 9;
            int s    = id3 % 18;
            int ntile = id3 / 18;
            int n = lane & 15, q = lane >> 4;
            int kap = s * 32 + q * 8 + j;
            int k = kap >> 6, c = kap & 63;
            int o = ntile * 16 + n;
            float v = (o < 18) ? offset_w[(o * 64 + c) * 9 + k] : 0.0f;
            OWb[id2] = __float2bfloat16(v);
        }
        return;
    }

    // ---- transpose path (XCD swizzle: 520 = 8*65)
    int blk = (raw & 7) * 65 + (raw >> 3);   // b*130 + r
    int b = blk / 130, r = blk - b * 130;
    unsigned* rowp = (unsigned*)(xBp + (size_t)(b * 130 + r) * 130 * 64); // 4160 dwords per row
    if (r == 0 || r == 129) {           // full zero row (halo)
        uint4 z = {0u, 0u, 0u, 0u};
        for (int i = 0; i < 5; ++i) {
            int e = i * 256 + t;
            if (e < 1040) ((uint4*)rowp)[e] = z;
        }
        return;
    }
    int h = r - 1;
    int w = t & 127, chalf = t >> 7;
    for (int i = 0; i < 32; ++i) {
        int c = i * 2 + chalf;
        lds[w * 65 + c] = x[((b * 64 + c) * 128 + h) * 128 + w];
    }
    __syncthreads();
    unsigned* dst = rowp + 32;          // col 1 (each col = 64 shorts = 32 dwords)
    for (int i = 0; i < 16; ++i) {
        int L = i * 256 + t;            // L = ww*32 + c2
        int ww = L >> 5, c2 = L & 31;
        float f0 = lds[ww * 65 + c2 * 2];
        float f1 = lds[ww * 65 + c2 * 2 + 1];
        unsigned pk = ((unsigned)bf16s(f0) & 0xffffu) | ((unsigned)bf16s(f1) << 16);
        dst[L] = pk;
    }
    if (t < 64) {                       // zero halo cols 0 and 129
        int col = (t >> 5) * 129;
        rowp[col * 32 + (t & 31)] = 0u;
    }
}

// ---------------------------------------------------------------- phase-4 sampling helper
// Lane owns 8 channels (c8*8..c8*8+7) of pixel p; taps K0..K1-1.
// Loop 1 issues ALL corner loads (statically-indexed reg arrays -> no scratch),
// loop 2 consumes. Zero-halo padding: clamp to [-1,128]; halo reads return 0.
template<int K0, int K1>
static __device__ inline void sample_taps(const __hip_bfloat16* __restrict__ xb8,
                                          const float* __restrict__ offL,
                                          short* __restrict__ sampB,
                                          int h, int w0, int p, int c8)
{
    constexpr int NT = K1 - K0;
    float wa[NT], wb_[NT], wc[NT], wd[NT];
    uint4 r0[NT], r1[NT], r2[NT], r3[NT];
#pragma unroll
    for (int i = 0; i < NT; ++i) {
        int k = K0 + i;
        float offy = offL[(2 * k) * 16 + p];
        float offx = offL[(2 * k + 1) * 16 + p];
        float py = (float)(h - 1 + (k / 3)) + offy;
        float px = (float)(w0 + p - 1 + (k % 3)) + offx;
        float y0f = floorf(py), x0f = floorf(px);
        float wy1 = py - y0f, wx1 = px - x0f;
        float wy0 = 1.0f - wy1, wx0 = 1.0f - wx1;
        int iy = (int)y0f, ix = (int)x0f;
        int iy0 = min(max(iy, -1), 128);
        int ix0 = min(max(ix, -1), 128);
        int iy1 = min(max(iy + 1, -1), 128);
        int ix1 = min(max(ix + 1, -1), 128);
        int rb0 = iy0 * 130, rb1 = iy1 * 130;
        r0[i] = *(const uint4*)(xb8 + (rb0 + ix0) * 64);
        r1[i] = *(const uint4*)(xb8 + (rb0 + ix1) * 64);
        r2[i] = *(const uint4*)(xb8 + (rb1 + ix0) * 64);
        r3[i] = *(const uint4*)(xb8 + (rb1 + ix1) * 64);
        wa[i] = wy0 * wx0;
        wb_[i] = wy0 * wx1;
        wc[i] = wy1 * wx0;
        wd[i] = wy1 * wx1;
    }
#pragma unroll
    for (int i = 0; i < NT; ++i) {
        int k = K0 + i;
        short8 pk;
#define SAMP1(idx, comp, EXT) { \
            float sv = fmaf(wd[i], EXT(r3[i].comp), fmaf(wc[i], EXT(r2[i].comp), \
                       fmaf(wb_[i], EXT(r1[i].comp), wa[i] * EXT(r0[i].comp)))); \
            pk[idx] = bf16s(sv); }
        SAMP1(0, x, lo2f) SAMP1(1, x, hi2f)
        SAMP1(2, y, lo2f) SAMP1(3, y, hi2f)
        SAMP1(4, z, lo2f) SAMP1(5, z, hi2f)
        SAMP1(6, w, lo2f) SAMP1(7, w, hi2f)
#undef SAMP1
        int s = 2 * k + (c8 >> 2);
        *(short8*)&sampB[(s * 16 + p) * 40 + (c8 & 3) * 8] = pk;
    }
}

// ---------------------------------------------------------------- fused offconv + sampling + deform conv
// block = 16x1 row tile; 4 waves; grid = 4096 (XCD-swizzled: 8*512)
// LDS = sampB 23040 (patch[54][80] aliases its head) + offL 1152 = 24192 B
// launch_bounds(256,4): VGPR cap 128 so the full gather tap-batch stays in flight.
__global__ __launch_bounds__(256, 4) void deform_kernel(
    const __hip_bfloat16* __restrict__ xBp, // [4][130][130][64] padded NHWC bf16
    const __hip_bfloat16* __restrict__ Wb,  // [4][18][64][8]
    const __hip_bfloat16* __restrict__ OWb, // [2][18][64][8]
    const float* __restrict__ offset_b,     // [18]
    const float* __restrict__ bias,         // [64]
    float* __restrict__ out)                // [4][64][128][128] NCHW
{
    __shared__ __align__(16) short sampB[18 * 16 * 40];  // 23040 B
    __shared__ __align__(16) float offL[288];            // [o][p] (separate — NOT aliased)

    int t = threadIdx.x, wv = t >> 6, lane = t & 63;
    int bid = (blockIdx.x & 7) * 512 + (blockIdx.x >> 3); // XCD swizzle: contiguous (b,h) per XCD
    int b  = bid >> 10;
    int h  = (bid >> 3) & 127;
    int w0 = (bid & 7) << 4;

    short* patch = sampB;            // [54 px][80 shorts]; px = row*18+col
                                     // rows = padded h..h+2, cols = padded w0..w0+17

    // ---- phase 1: stage 3x18x64 patch bf16 — branchless (halo is pre-zeroed), 16-B chunks
    {
#pragma unroll
        for (int i = 0; i < 2; ++i) {
            int e = i * 256 + t;            // 54*8 = 432 chunks of 16 B
            if (e < 432) {
                int px = e >> 3, part = e & 7;
                int row = px / 18, col = px - row * 18;
                const uint4* src = (const uint4*)(xBp +
                    ((size_t)((b * 130 + h + row) * 130) + w0 + col) * 64 + part * 8);
                *(uint4*)&patch[px * 80 + part * 8] = *src;
            }
        }
    }
    __syncthreads();

    // ---- phase 2: offset conv via MFMA (waves 0,1; o = wv*16+n; pixel p = q*4+reg)
    if (wv < 2) {
        int n = lane & 15, q = lane >> 4;
        const short8* Bw = (const short8*)OWb + (wv * 18) * 64 + lane;
        f32x4 acc = {0.f, 0.f, 0.f, 0.f};
#pragma unroll
        for (int s = 0; s < 18; ++s) {
            int k = s >> 1;
            int ky = k / 3, kx = k - ky * 3;
            int pix = ky * 18 + n + kx;
            const short8 a = *(const short8*)&patch[pix * 80 + (s & 1) * 32 + q * 8];
            acc = __builtin_amdgcn_mfma_f32_16x16x32_bf16(a, Bw[s * 64], acc, 0, 0, 0);
        }
        int o = wv * 16 + n;
        if (o < 18) {
            float bo = offset_b[o];
#pragma unroll
            for (int r = 0; r < 4; ++r)
                offL[o * 16 + q * 4 + r] = acc[r] + bo;
        }
    }
    __syncthreads();

    // ---- phase 4: sampling; 8 lanes/pixel (lane owns 8 channels), taps split over wave pairs
    // waves 0,1: taps 0..3; waves 2,3: taps 4..8. p = (wv&1)*8 + (lane>>3).
    // (sampB overwrites patch — safe: patch last read in phase 2, barrier between.)
    {
        int g8 = lane >> 3, c8 = lane & 7;
        int p = (wv & 1) * 8 + g8;
        const __hip_bfloat16* xb8 = xBp + (size_t)b * (130 * 130 * 64) + c8 * 8 + 131 * 64;
        if (wv < 2) sample_taps<0, 4>(xb8, offL, sampB, h, w0, p, c8);
        else        sample_taps<4, 9>(xb8, offL, sampB, h, w0, p, c8);
    }
    __syncthreads();

    // ---- phase 5: einsum via MFMA; wave wv = o-tile; 18 K-steps
    {
        int n = lane & 15, q = lane >> 4;
        int arow = n * 40 + q * 8;          // A: m = pixel = lane&15
        const short8* BwW = (const short8*)Wb + (wv * 18) * 64 + lane;
        f32x4 acc = {0.f, 0.f, 0.f, 0.f};
#pragma unroll
        for (int s = 0; s < 18; ++s) {
            const short8 a = *(const short8*)&sampB[s * 640 + arow];
            acc = __builtin_amdgcn_mfma_f32_16x16x32_bf16(a, BwW[s * 64], acc, 0, 0, 0);
        }
        int o = wv * 16 + n;
        float bo = bias[o];
        // C/D: col = o, row m = q*4+reg = pixel -> w = w0 + q*4 + reg
        float4 st = {acc[0] + bo, acc[1] + bo, acc[2] + bo, acc[3] + bo};
        *(float4*)&out[(((size_t)b * 64 + o) * 128 + h) * 128 + w0 + q * 4] = st;
    }
}

// ---------------------------------------------------------------- launch
extern "C" void kernel_launch(void* const* d_in, const int* in_sizes, int n_in,
                              void* d_out, int out_size, void* d_ws, size_t ws_size,
                              hipStream_t stream) {
    const float* x        = (const float*)d_in[0];
    const float* offset_w = (const float*)d_in[1];
    const float* offset_b = (const float*)d_in[2];
    const float* weight   = (const float*)d_in[3];
    const float* bias     = (const float*)d_in[4];
    char* ws = (char*)d_ws;
    __hip_bfloat16* xBp = (__hip_bfloat16*)ws;                          // 8,652,800 B
    __hip_bfloat16* Wb  = (__hip_bfloat16*)(ws + 8652800);              // 73,728 B
    __hip_bfloat16* OWb = (__hip_bfloat16*)(ws + 8652800 + 73728);      // 36,864 B
    float* outp = (float*)d_out;

    hipLaunchKernelGGL(prep_transpose_kernel, dim3(736),  dim3(256), 0, stream,
                       x, xBp, offset_w, weight, Wb, OWb);
    hipLaunchKernelGGL(deform_kernel,         dim3(4096), dim3(256), 0, stream,
                       xBp, Wb, OWb, offset_b, bias, outp);
}